// Round 12
// baseline (141.240 us; speedup 1.0000x reference)
//
#include <hip/hip_runtime.h>
#include <math.h>

#define NPTS 4096
#define NSMP 10

typedef float f32x2 __attribute__((ext_vector_type(2)));

// ======== single fused kernel: inline prep + topk (rows=8, float4) + mlp epilogue ======
// 1024 threads (16 waves), grid 32x8 = 256 blocks = 1/CU. 16 waves/CU is STRUCTURAL:
// arch-VGPR pool = 256/SIMD (empirical law fitting R3-R11: waves/SIMD = 256/VGPR;
// 2 co-resident 1024-thr blocks need VGPR<=32 -> unavoidable ~25-dword spill, R8).
// So: minimize per-row work at 16 waves. rows=8/wave + float4 pts (sq precomputed)
// -> 1 ds_read_b128 per candidate serves 8 rows (4x less DS/row than rows=4 xyz),
// no per-candidate sq VALU. __launch_bounds__(1024,4): 64-VGPR budget (R5 fit 52).
//
// LDS (~110.5 KB): pts4 64K | trans 33.28K (w2p staging -> per-wave bufi -> out
// transpose; phases separated by barriers / program order) | wl 7.5K | nbrL/cnt/bl.
//
// prep (inline, every block): Wn[sc][p]=sum_o w2[p][o]*(w1[o][k1](+w1[o][k2])),
// bb[p]=b2[p]+sum_o w2[p][o]*b1[o]. w2 staged PADDED (o*65+p: conflict-free column
// reads); w1/b1 indices forced wave-uniform via readfirstlane -> s_load (R10's
// regression was vector-global uniform loads; this is the fix). occ tables verified
// by R10 (identical absmax).
//
// topk: exact 10-NN per row, f64-ranked (np-f64 reference order):
//   pass1: key = sqm - 2*dot via 3 pk-fma (q pre-scaled by -2); per-row lane minima.
//   tau:   MSB-first radix-select, 8 rows interleaved; prefix wave-uniform -> SGPR.
//          T=pfx|0xFF >= row's 10th-smallest lane-min >= 10th-smallest key.
//   pass2: recompute keys (IDENTICAL formula -> superset; slack 2e-4 >> |f32-f64|),
//          push survivors to per-wave bufi (aliases trans slice).
//   pass3: f64 re-rank via readlane rank-count, j-major; rank = output slot.
//   epi:   acc[p=lane] over 10 nbrs (wl/bl), per-wave transpose slice (pad 65),
//          barrier, coalesced float4 stores (full 256B runs).
__global__ __launch_bounds__(1024, 4) void topk_kernel(const float* __restrict__ pos,
                                                       const float* __restrict__ w1,
                                                       const float* __restrict__ b1,
                                                       const float* __restrict__ w2,
                                                       const float* __restrict__ b2,
                                                       float* __restrict__ out) {
  __shared__ float4 pts[NPTS];         // 64 KB (x,y,z,sq)
  __shared__ float  trans[16 * 520];   // 33.28 KB: w2p (o*65+p, 4160 f) / bufi / out-T
  __shared__ float  wl[30 * 64];       // 7.5 KB fused Wn
  __shared__ float  bl[64];
  __shared__ int    nbrL[16][8][NSMP]; // 5 KB
  __shared__ int    cnt[16][8];

  const int b = blockIdx.y, tid = threadIdx.x, lane = tid & 63, wv = tid >> 6;
  const float* pb = pos + (size_t)b * 3 * NPTS;
  for (int i = tid; i < NPTS; i += 1024) {
    float x = pb[i], y = pb[i + NPTS], z = pb[i + 2 * NPTS];
    float sq = fmaf(z, z, fmaf(y, y, x * x));   // same formula as key uses -> exact
    pts[i] = make_float4(x, y, z, sq);
  }
  // stage w2 transposed+padded: w2p[o*65+p] = w2[p*64+o] (bank-conflict-free both ways)
  for (int idx = tid; idx < 4096; idx += 1024)
    trans[(idx & 63) * 65 + (idx >> 6)] = w2[idx];
  __syncthreads();

  // ---- inline prep: waves 0..14 do Wn cols {wv, wv+15}; wave 15 does bias ----
  {
    const int occN[10] = {1,1,2,2,2,2,2,2,1,1};
    const int occG[10][2] = {{0,0},{2,0},{0,3},{1,2},{0,3},{1,2},{0,3},{1,2},{3,0},{1,0}};
    const int occQ[10][2] = {{0,0},{0,0},{1,0},{0,1},{2,1},{1,2},{3,2},{2,3},{3,0},{3,0}};
    if (wv < 15) {
      #pragma unroll
      for (int slot = 0; slot < 2; ++slot) {
        int sc = wv + 15 * slot;
        int s = sc / 3, cc = sc - 3 * s;
        // force wave-uniform -> SGPR -> s_load for the w1 reads (R10 fix)
        int k1 = __builtin_amdgcn_readfirstlane((cc + 3 * occG[s][0]) * 4 + occQ[s][0]);
        int k2 = __builtin_amdgcn_readfirstlane((cc + 3 * occG[s][1]) * 4 + occQ[s][1]);
        int two = __builtin_amdgcn_readfirstlane(occN[s] - 1);
        float acc = 0.0f;
        #pragma unroll 8
        for (int o = 0; o < 64; ++o) {
          float wsum = w1[o * 48 + k1];
          if (two) wsum += w1[o * 48 + k2];
          acc = fmaf(trans[o * 65 + lane], wsum, acc);
        }
        wl[sc * 64 + lane] = acc;
      }
    } else {
      float acc = b2[lane];
      #pragma unroll 8
      for (int o = 0; o < 64; ++o)
        acc = fmaf(trans[o * 65 + lane], b1[o], acc);   // b1[o]: literal o -> s_load
      bl[lane] = acc;
    }
  }
  __syncthreads();   // wl/bl ready; w2p dead -> trans reusable as bufi

  const int nb = blockIdx.x * 128;      // block's first row
  const int n0 = nb + wv * 8;           // wave's first row
  float* transF = &trans[wv * 520];     // this wave's private slice
  int*   bufiW  = (int*)transF;         // survivor buffer: r*64+slot (512 ints <= 520)

  // 8 queries, pair-packed, -2 folded (filter-only arithmetic)
  f32x2 qx2[4], qy2[4], qz2[4], dmin[4];
  #pragma unroll
  for (int pp = 0; pp < 4; ++pp) {
    float4 qa = pts[n0 + 2 * pp], qb = pts[n0 + 2 * pp + 1];
    qx2[pp].x = -2.0f * qa.x; qx2[pp].y = -2.0f * qb.x;
    qy2[pp].x = -2.0f * qa.y; qy2[pp].y = -2.0f * qb.y;
    qz2[pp].x = -2.0f * qa.z; qz2[pp].y = -2.0f * qb.z;
    dmin[pp].x = INFINITY; dmin[pp].y = INFINITY;
  }

  // ---- pass 1: per-row lane minima (1 ds_read_b128 per candidate serves 8 rows) ----
  #pragma unroll 8
  for (int k = 0; k < 64; ++k) {
    float4 p = pts[k * 64 + lane];
    #pragma unroll
    for (int pp = 0; pp < 4; ++pp) {
      f32x2 key = qx2[pp] * p.x + p.w;
      key = qy2[pp] * p.y + key;
      key = qz2[pp] * p.z + key;
      dmin[pp] = __builtin_elementwise_min(dmin[pp], key);
    }
  }

  // ---- tau: MSB-first radix-select (prefix in SGPRs), 8 rows interleaved ----
  unsigned um[8];
  #pragma unroll
  for (int r = 0; r < 8; ++r) {
    float dm = (r & 1) ? dmin[r >> 1].y : dmin[r >> 1].x;
    unsigned ub = __float_as_uint(dm);
    um[r] = (ub & 0x80000000u) ? ~ub : (ub | 0x80000000u);
  }
  unsigned pfx[8] = {0u,0u,0u,0u,0u,0u,0u,0u};
  #pragma unroll 1
  for (int bno = 31; bno >= 8; --bno) {
    const unsigned bit = 1u << bno, ones = bit - 1u;
    #pragma unroll
    for (int r = 0; r < 8; ++r)
      if (__popcll(__ballot(um[r] <= (pfx[r] | ones))) < NSMP) pfx[r] |= bit;
  }
  float tx[8];
  #pragma unroll
  for (int r = 0; r < 8; ++r) {
    unsigned T = pfx[r] | 0xFFu;
    unsigned tb = (T & 0x80000000u) ? (T ^ 0x80000000u) : ~T;
    float tf = __uint_as_float(tb);
    tx[r] = __fadd_rn(__fadd_rn(tf, 2e-4f), __fmul_rn(fabsf(tf), 1e-5f));
  }

  if (lane < 8) cnt[wv][lane] = 0;     // same-wave DS ops are in-order

  // ---- pass 2: recompute keys (identical formula), push survivors per row ----
  #pragma unroll 4
  for (int k = 0; k < 64; ++k) {
    float4 p = pts[k * 64 + lane];
    #pragma unroll
    for (int pp = 0; pp < 4; ++pp) {
      f32x2 key = qx2[pp] * p.x + p.w;
      key = qy2[pp] * p.y + key;
      key = qz2[pp] * p.z + key;
      if (key.x <= tx[2 * pp]) {
        int ps = atomicAdd(&cnt[wv][2 * pp], 1);
        if (ps < 64) bufiW[(2 * pp) * 64 + ps] = k * 64 + lane;
      }
      if (key.y <= tx[2 * pp + 1]) {
        int ps = atomicAdd(&cnt[wv][2 * pp + 1], 1);
        if (ps < 64) bufiW[(2 * pp + 1) * 64 + ps] = k * 64 + lane;
      }
    }
  }

  // ---- pass 3: f64 re-rank via readlane rank-count, j-major (8-way ILP) ----
  int c[8], si[8], rank[8];
  double dd[8];
  int cmax = 0;
  #pragma unroll
  for (int r = 0; r < 8; ++r) {
    c[r] = __builtin_amdgcn_readfirstlane(cnt[wv][r]);
    if (c[r] > 64) c[r] = 64;
    cmax = (c[r] > cmax) ? c[r] : cmax;
    rank[r] = 0;
  }
  #pragma unroll
  for (int r = 0; r < 8; ++r) {
    float4 qa = pts[n0 + r];
    if (lane < c[r]) {
      si[r] = bufiW[r * 64 + lane];
      float4 p = pts[si[r]];
      double dqx = (double)qa.x, dqy = (double)qa.y, dqz = (double)qa.z;
      double dpx = (double)p.x, dpy = (double)p.y, dpz = (double)p.z;
      double dot = dqx * dpx + dqy * dpy + dqz * dpz;
      double sqn = dqx * dqx + dqy * dqy + dqz * dqz;
      double sqm = dpx * dpx + dpy * dpy + dpz * dpz;
      dd[r] = (sqn - 2.0 * dot) + sqm;             // self -> exactly 0.0
    } else { dd[r] = (double)INFINITY; si[r] = 0x7FFFFFFF; }
  }
  #pragma unroll 1
  for (int j = 0; j < cmax; ++j) {
    #pragma unroll
    for (int r = 0; r < 8; ++r) {
      int jlo = __builtin_amdgcn_readlane(__double2loint(dd[r]), j);
      int jhi = __builtin_amdgcn_readlane(__double2hiint(dd[r]), j);
      int ji  = __builtin_amdgcn_readlane(si[r], j);
      double jd = __hiloint2double(jhi, jlo);
      if (jd < dd[r] || (jd == dd[r] && ji < si[r])) ++rank[r];
    }
  }
  #pragma unroll
  for (int r = 0; r < 8; ++r)
    if (lane < c[r] && rank[r] < NSMP)
      nbrL[wv][r][rank[r]] = si[r];

  // ---- epilogue: acc then per-wave transpose slice (bufiW dead after pass3 reads) ----
  #pragma unroll 1
  for (int r = 0; r < 8; ++r) {
    float a = bl[lane];
    #pragma unroll
    for (int s = 0; s < NSMP; ++s) {
      int id = nbrL[wv][r][s];          // uniform -> broadcast ds_read
      float4 pv = pts[id];
      a = fmaf(wl[(s * 3 + 0) * 64 + lane], pv.x, a);
      a = fmaf(wl[(s * 3 + 1) * 64 + lane], pv.y, a);
      a = fmaf(wl[(s * 3 + 2) * 64 + lane], pv.z, a);
    }
    transF[r * 65 + lane] = a;          // padded row -> conflict-free
  }
  __syncthreads();

  // coalesced store: thread (p = tid>>5 (+32*it), t32 = tid&31) writes n = nb+4*t32..+3
  #pragma unroll
  for (int it = 0; it < 2; ++it) {
    int p = (tid >> 5) + 32 * it, t32 = tid & 31;
    const float* src = &trans[(t32 >> 1) * 520 + (t32 & 1) * 4 * 65 + p];
    float4 v;
    v.x = src[0 * 65]; v.y = src[1 * 65]; v.z = src[2 * 65]; v.w = src[3 * 65];
    *(float4*)(out + ((size_t)b * 64 + p) * NPTS + nb + 4 * t32) = v;
  }
}

extern "C" void kernel_launch(void* const* d_in, const int* in_sizes, int n_in,
                              void* d_out, int out_size, void* d_ws, size_t ws_size,
                              hipStream_t stream) {
  (void)in_sizes; (void)n_in; (void)out_size; (void)d_ws; (void)ws_size;
  const float* pos = (const float*)d_in[0];
  const float* w1  = (const float*)d_in[1];
  const float* b1  = (const float*)d_in[2];
  const float* w2  = (const float*)d_in[3];
  const float* b2  = (const float*)d_in[4];
  float* out = (float*)d_out;

  topk_kernel<<<dim3(32, 8), dim3(1024), 0, stream>>>(pos, w1, b1, w2, b2, out);
}

// Round 13
// 133.765 us; speedup vs baseline: 1.0559x; 1.0559x over previous
//
#include <hip/hip_runtime.h>
#include <math.h>

#define NPTS 4096
#define NSMP 10
#define WAVES 12   // 768-thread blocks

typedef float f32x2 __attribute__((ext_vector_type(2)));

// ---------------- prep: fuse (w1,b1,w2,b2) -> Wn[30][64] ([s*3+c][p]), bb[64] ----------
// out[p] = bb[p] + sum_{s,c} Wn[s*3+c][p] * pos[b,c,idx_s]  (no nonlinearity -> legal).
__global__ __launch_bounds__(256) void prep_kernel(
    const float* __restrict__ w1, const float* __restrict__ b1,
    const float* __restrict__ w2, const float* __restrict__ b2,
    float* __restrict__ wn, float* __restrict__ bb) {
  __shared__ float w1l[64 * 48];      // 12 KB, [o][k]
  __shared__ float w2t[64 * 64];      // 16 KB, transposed [o][p] (lane reads stride-1)
  __shared__ float b1l[64];
  __shared__ float part[4][30][64];   // 30 KB
  __shared__ float bpart[4][64];
  const int t = threadIdx.x, p = t & 63, grp = t >> 6, o0 = grp * 16;
  for (int idx = t; idx < 64 * 48; idx += 256) w1l[idx] = w1[idx];
  for (int idx = t; idx < 64 * 64; idx += 256) w2t[(idx & 63) * 64 + (idx >> 6)] = w2[idx];
  if (t < 64) b1l[t] = b1[t];
  __syncthreads();

  const int sg[16] = {0,2,4,6, 3,5,7,9, 1,3,5,7, 2,4,6,8};
  float w2r[16];
  #pragma unroll
  for (int oo = 0; oo < 16; ++oo) w2r[oo] = w2t[(o0 + oo) * 64 + p];
  float wloc[30];
  #pragma unroll
  for (int i = 0; i < 30; ++i) wloc[i] = 0.0f;
  #pragma unroll
  for (int g = 0; g < 4; ++g)
    #pragma unroll
    for (int i = 0; i < 2; ++i)
      #pragma unroll
      for (int j = 0; j < 2; ++j) {
        const int s = sg[g * 4 + i * 2 + j];
        #pragma unroll
        for (int c = 0; c < 3; ++c) {
          const int k = (c + 3 * g) * 4 + i * 2 + j;   // w1 flat index over (12,2,2)
          float wk = 0.0f;
          #pragma unroll
          for (int oo = 0; oo < 16; ++oo)
            wk = fmaf(w2r[oo], w1l[(o0 + oo) * 48 + k], wk);  // w1l read is broadcast
          wloc[s * 3 + c] += wk;
        }
      }
  #pragma unroll
  for (int i = 0; i < 30; ++i) part[grp][i][p] = wloc[i];
  float sb = 0.0f;
  #pragma unroll
  for (int oo = 0; oo < 16; ++oo) sb = fmaf(w2r[oo], b1l[o0 + oo], sb);
  bpart[grp][p] = sb;
  __syncthreads();
  const float* p0 = &part[0][0][0];
  for (int idx = t; idx < 30 * 64; idx += 256)
    wn[idx] = p0[idx] + p0[1920 + idx] + p0[3840 + idx] + p0[5760 + idx];
  if (t < 64) bb[t] = b2[t] + bpart[0][t] + bpart[1][t] + bpart[2][t] + bpart[3][t];
}

// ---------------- fused topk + mlp: 768-thr blocks -> 24 waves/CU ---------------------
// The R3-R12 ledger pins the law: waves/SIMD = 256/VGPR, and occupancy is quantized by
// BLOCK size. 1024-thr blocks can never exceed 16 waves/CU without VGPR<=32 (= spill,
// R8). 768-thr blocks (12 waves) at LDS ~70 KB -> 2 blocks/CU = 24 waves/CU, needing
// only VGPR<=42 (launch_bounds(768,6) -> budget floor(256/6)=42; this body measured 36
// at R11). Body is EXACTLY R11's (rows=4/wave, xy/z planes, radix-select tau, f64
// re-rank) -> bit-identical output. Grid 86x8: block 85 is 1/4-active (guarded; idle
// waves skip compute but reach both barriers).
//   pass1: b64+b32 per candidate serves 4 rows (pair-packed pk-fma); lane minima.
//   tau:   MSB-first radix-select; prefix wave-uniform -> SGPRs. T=pfx|0xFF >= row's
//          10th-smallest f32 key; slack 2e-4 >> |f32-f64| (~4e-5) -> superset filter.
//   pass2: recompute keys (identical formula), push survivors to per-wave bufi.
//   pass3: f64 re-rank (np-f64 reference order; self -> exact 0.0) via readlane
//          rank-count, j-major; rank = output slot.
//   epi:   mlp acc[p=lane]; per-wave transpose slice (pad 65); barrier; stores in
//          192B runs = 3 full 64B lines each (no partial-line RMW).
__global__ __launch_bounds__(768, 6) void topk_kernel(const float* __restrict__ pos,
                                                      const float* __restrict__ wng,
                                                      const float* __restrict__ bbg,
                                                      float* __restrict__ out) {
  __shared__ f32x2 ptsxy[NPTS];          // 32 KB (x,y)
  __shared__ float ptsz[NPTS];           // 16 KB (z)
  __shared__ float trans[WAVES * 260];   // 12.19 KB; per-wave slice (bufi -> out-T)
  __shared__ float wl[30 * 64];          // 7.5 KB Wn
  __shared__ float bl[64];
  __shared__ int   nbrL[WAVES][4][NSMP]; // 1.875 KB
  __shared__ int   cnt[WAVES][4];

  const int b = blockIdx.y, tid = threadIdx.x, lane = tid & 63, wv = tid >> 6;
  const float* pb = pos + (size_t)b * 3 * NPTS;
  for (int i = tid; i < NPTS; i += 768) {
    f32x2 xy; xy.x = pb[i]; xy.y = pb[i + NPTS];
    ptsxy[i] = xy;
    ptsz[i]  = pb[i + 2 * NPTS];
  }
  for (int i = tid; i < 30 * 64; i += 768) wl[i] = wng[i];
  if (tid < 64) bl[tid] = bbg[tid];
  __syncthreads();

  const int nb = blockIdx.x * 4 * WAVES;  // block's first row (48 rows/block)
  const int n0 = nb + wv * 4;             // wave's first row
  const bool active = (n0 < NPTS);        // wave-uniform (block 85 is 1/4-active)
  float* transF = &trans[wv * 260];       // this wave's private slice
  int*   bufiW  = (int*)transF;           // survivor buffer: r*64+slot (256 ints)

  if (active) {
    // 4 queries, pair-packed, -2 folded (filter-only arithmetic)
    f32x2 qx2[2], qy2[2], qz2[2], dmin[2];
    #pragma unroll
    for (int pp = 0; pp < 2; ++pp) {
      int na = n0 + 2 * pp;
      f32x2 qa = ptsxy[na], qb = ptsxy[na + 1];
      qx2[pp].x = -2.0f * qa.x; qx2[pp].y = -2.0f * qb.x;
      qy2[pp].x = -2.0f * qa.y; qy2[pp].y = -2.0f * qb.y;
      qz2[pp].x = -2.0f * ptsz[na]; qz2[pp].y = -2.0f * ptsz[na + 1];
      dmin[pp].x = INFINITY; dmin[pp].y = INFINITY;
    }

    // ---- pass 1: per-row lane minima (b64 + b32 per candidate, serves 4 rows) ----
    #pragma unroll 2
    for (int k = 0; k < 64; ++k) {
      int m = k * 64 + lane;
      f32x2 xy = ptsxy[m];
      float z = ptsz[m];
      float sq = fmaf(z, z, fmaf(xy.y, xy.y, xy.x * xy.x));
      f32x2 sq2; sq2.x = sq; sq2.y = sq;
      #pragma unroll
      for (int pp = 0; pp < 2; ++pp) {
        f32x2 key = qx2[pp] * xy.x + sq2;
        key = qy2[pp] * xy.y + key;
        key = qz2[pp] * z + key;
        dmin[pp] = __builtin_elementwise_min(dmin[pp], key);
      }
    }

    // ---- tau: MSB-first radix-select; prefix is wave-uniform (SGPRs) ----
    unsigned um[4];
    #pragma unroll
    for (int r = 0; r < 4; ++r) {
      float dm = (r & 1) ? dmin[r >> 1].y : dmin[r >> 1].x;
      unsigned ub = __float_as_uint(dm);
      um[r] = (ub & 0x80000000u) ? ~ub : (ub | 0x80000000u);
    }
    unsigned pfx0 = 0u, pfx1 = 0u, pfx2 = 0u, pfx3 = 0u;
    #pragma unroll 1
    for (int bno = 31; bno >= 8; --bno) {
      const unsigned bit = 1u << bno, ones = bit - 1u;
      if (__popcll(__ballot(um[0] <= (pfx0 | ones))) < NSMP) pfx0 |= bit;
      if (__popcll(__ballot(um[1] <= (pfx1 | ones))) < NSMP) pfx1 |= bit;
      if (__popcll(__ballot(um[2] <= (pfx2 | ones))) < NSMP) pfx2 |= bit;
      if (__popcll(__ballot(um[3] <= (pfx3 | ones))) < NSMP) pfx3 |= bit;
    }
    float tx[4];
    #pragma unroll
    for (int r = 0; r < 4; ++r) {
      unsigned T = ((r == 0) ? pfx0 : (r == 1) ? pfx1 : (r == 2) ? pfx2 : pfx3) | 0xFFu;
      unsigned tb = (T & 0x80000000u) ? (T ^ 0x80000000u) : ~T;
      float tf = __uint_as_float(tb);
      tx[r] = __fadd_rn(__fadd_rn(tf, 2e-4f), __fmul_rn(fabsf(tf), 1e-5f));
    }

    if (lane < 4) cnt[wv][lane] = 0;     // same-wave DS ops are in-order

    // ---- pass 2: recompute keys (identical formula), push survivors ----
    #pragma unroll 2
    for (int k = 0; k < 64; ++k) {
      int m = k * 64 + lane;
      f32x2 xy = ptsxy[m];
      float z = ptsz[m];
      float sq = fmaf(z, z, fmaf(xy.y, xy.y, xy.x * xy.x));
      f32x2 sq2; sq2.x = sq; sq2.y = sq;
      #pragma unroll
      for (int pp = 0; pp < 2; ++pp) {
        f32x2 key = qx2[pp] * xy.x + sq2;
        key = qy2[pp] * xy.y + key;
        key = qz2[pp] * z + key;
        if (key.x <= tx[2 * pp]) {
          int ps = atomicAdd(&cnt[wv][2 * pp], 1);
          if (ps < 64) bufiW[(2 * pp) * 64 + ps] = m;
        }
        if (key.y <= tx[2 * pp + 1]) {
          int ps = atomicAdd(&cnt[wv][2 * pp + 1], 1);
          if (ps < 64) bufiW[(2 * pp + 1) * 64 + ps] = m;
        }
      }
    }

    // ---- pass 3: f64 re-rank via readlane rank-count, j-major ----
    int c[4], si[4], rank[4];
    double dd[4];
    int cmax = 0;
    #pragma unroll
    for (int r = 0; r < 4; ++r) {
      c[r] = __builtin_amdgcn_readfirstlane(cnt[wv][r]);
      if (c[r] > 64) c[r] = 64;
      cmax = (c[r] > cmax) ? c[r] : cmax;
      rank[r] = 0;
    }
    #pragma unroll
    for (int r = 0; r < 4; ++r) {
      int nq = n0 + r;
      f32x2 qxy = ptsxy[nq];
      float qzf = ptsz[nq];
      if (lane < c[r]) {
        si[r] = bufiW[r * 64 + lane];
        f32x2 pxy = ptsxy[si[r]];
        float pz = ptsz[si[r]];
        double dqx = (double)qxy.x, dqy = (double)qxy.y, dqz = (double)qzf;
        double dpx = (double)pxy.x, dpy = (double)pxy.y, dpz = (double)pz;
        double dot = dqx * dpx + dqy * dpy + dqz * dpz;
        double sqn = dqx * dqx + dqy * dqy + dqz * dqz;
        double sqm = dpx * dpx + dpy * dpy + dpz * dpz;
        dd[r] = (sqn - 2.0 * dot) + sqm;             // self -> exactly 0.0
      } else { dd[r] = (double)INFINITY; si[r] = 0x7FFFFFFF; }
    }
    #pragma unroll 1
    for (int j = 0; j < cmax; ++j) {
      #pragma unroll
      for (int r = 0; r < 4; ++r) {
        int jlo = __builtin_amdgcn_readlane(__double2loint(dd[r]), j);
        int jhi = __builtin_amdgcn_readlane(__double2hiint(dd[r]), j);
        int ji  = __builtin_amdgcn_readlane(si[r], j);
        double jd = __hiloint2double(jhi, jlo);
        if (jd < dd[r] || (jd == dd[r] && ji < si[r])) ++rank[r];
      }
    }
    #pragma unroll
    for (int r = 0; r < 4; ++r)
      if (lane < c[r] && rank[r] < NSMP)
        nbrL[wv][r][rank[r]] = si[r];

    // ---- epilogue: acc then per-wave transpose slice (bufiW dead now) ----
    #pragma unroll 1
    for (int r = 0; r < 4; ++r) {
      float a = bl[lane];
      #pragma unroll
      for (int s = 0; s < NSMP; ++s) {
        int id = nbrL[wv][r][s];          // uniform -> broadcast ds_read
        f32x2 pxy = ptsxy[id];
        float pz = ptsz[id];
        a = fmaf(wl[(s * 3 + 0) * 64 + lane], pxy.x, a);
        a = fmaf(wl[(s * 3 + 1) * 64 + lane], pxy.y, a);
        a = fmaf(wl[(s * 3 + 2) * 64 + lane], pz, a);
      }
      transF[r * 65 + lane] = a;          // padded row -> conflict-free
    }
  }
  __syncthreads();

  // store: thread (g = tid%12, p = tid/12) writes n = nb+4g..+3 for channel p.
  // 12 consecutive threads cover one p's 48 floats = 192 B = 3 full 64B lines.
  {
    int g = tid % WAVES, p = tid / WAVES;
    int n4 = nb + 4 * g;
    if (n4 < NPTS) {
      const float* src = &trans[g * 260 + p];
      float4 v;
      v.x = src[0 * 65]; v.y = src[1 * 65]; v.z = src[2 * 65]; v.w = src[3 * 65];
      *(float4*)(out + ((size_t)b * 64 + p) * NPTS + n4) = v;
    }
  }
}

extern "C" void kernel_launch(void* const* d_in, const int* in_sizes, int n_in,
                              void* d_out, int out_size, void* d_ws, size_t ws_size,
                              hipStream_t stream) {
  (void)in_sizes; (void)n_in; (void)out_size; (void)ws_size;
  const float* pos = (const float*)d_in[0];
  const float* w1  = (const float*)d_in[1];
  const float* b1  = (const float*)d_in[2];
  const float* w2  = (const float*)d_in[3];
  const float* b2  = (const float*)d_in[4];
  float* out = (float*)d_out;

  // workspace: Wn (30*64 f32) then bb (64 f32)
  float* wn = (float*)d_ws;
  float* bb = (float*)((char*)d_ws + 30 * 64 * 4);

  prep_kernel<<<dim3(1), dim3(256), 0, stream>>>(w1, b1, w2, b2, wn, bb);
  topk_kernel<<<dim3(86, 8), dim3(768), 0, stream>>>(pos, wn, bb, out);
}